// Round 4
// baseline (354.389 us; speedup 1.0000x reference)
//
#include <hip/hip_runtime.h>

// Problem constants
#define BB 8
#define NN 512
#define TT 64
#define SS 65      // T+1
#define DD 256
#define HH 256
#define G4 1024    // 4*H

// fast transcendentals (v_rcp_f32 based, ~1e-5 rel err; saturate at +-inf)
__device__ __forceinline__ float fsigmoid(float x) {
    return __builtin_amdgcn_rcpf(1.f + __expf(-x));
}
__device__ __forceinline__ float ftanh(float x) {
    float e = __expf(2.f * x);
    return fmaf(-2.f, __builtin_amdgcn_rcpf(e + 1.f), 1.f);
}

// ---------------------------------------------------------------------------
// combined: blocks [0,144): xg0 = seq @ w_ih[0]^T + b_ih[0] + b_hh[0]
//   (seq rows synthesized on the fly from init_i/lstm_in — never materialized)
// blocks [144,1200): init S0/S1 (h,tag) slot arrays (re-init每 launch: replay-safe)
// ---------------------------------------------------------------------------
__global__ void __launch_bounds__(256) xgprep_kernel(
    const float* __restrict__ lstm_in, const float* __restrict__ init_i,
    const float* __restrict__ init_h, const float* __restrict__ w_ih,
    const float* __restrict__ b_ih, const float* __restrict__ b_hh,
    float* __restrict__ xg0,
    unsigned long long* __restrict__ S0, unsigned long long* __restrict__ S1)
{
    const int tid = threadIdx.x;
    if (blockIdx.x >= 144) {
        int i = (blockIdx.x - 144) * 256 + tid;   // [0, 270336)
        if (i < 2048) {
            S0[i] = (1ULL << 32) | (unsigned long long)(unsigned)__float_as_uint(init_h[i & 255]);
        } else if (i < 4096) {
            S1[i - 2048] = (1ULL << 32)
                         | (unsigned long long)(unsigned)__float_as_uint(init_h[HH + (i & 255)]);
        } else if (i < 4096 + 65 * 2048) {
            S0[2048 + (i - 4096)] = 0ULL;
        } else {
            S1[2048 + (i - (4096 + 65 * 2048))] = 0ULL;
        }
        return;
    }
    __shared__ float As[16][68];
    __shared__ float Bs[16][68];
    const int bm = ((int)blockIdx.x % 9) * 64, bn = ((int)blockIdx.x / 9) * 64;
    const int tm = (tid >> 4) * 4, tn = (tid & 15) * 4;
    const int arow = tid >> 2, akq = (tid & 3) << 2;
    float acc[4][4] = {};
    for (int k0 = 0; k0 < 256; k0 += 16) {
        {   // synthesize seq row m = b*65+s : s==0 -> init_i, else lstm_in[b, s-1]
            int m = bm + arow;
            float4 v = make_float4(0.f, 0.f, 0.f, 0.f);
            if (m < 520) {
                int s = m % 65, b = m / 65;
                const float* src = (s == 0) ? (init_i + k0 + akq)
                                            : (lstm_in + ((size_t)b * TT + (s - 1)) * DD + k0 + akq);
                v = *(const float4*)src;
            }
            As[akq + 0][arow] = v.x; As[akq + 1][arow] = v.y;
            As[akq + 2][arow] = v.z; As[akq + 3][arow] = v.w;
        }
        {   // B[N,K] transposed
            int n = bn + arow;
            float4 v = *(const float4*)(w_ih + (size_t)n * 256 + k0 + akq);
            Bs[akq + 0][n - bn] = v.x; Bs[akq + 1][n - bn] = v.y;
            Bs[akq + 2][n - bn] = v.z; Bs[akq + 3][n - bn] = v.w;
        }
        __syncthreads();
#pragma unroll
        for (int kk = 0; kk < 16; ++kk) {
            float4 a = *(const float4*)&As[kk][tm];
            float4 b = *(const float4*)&Bs[kk][tn];
            float av[4] = {a.x, a.y, a.z, a.w};
            float bv[4] = {b.x, b.y, b.z, b.w};
#pragma unroll
            for (int i = 0; i < 4; ++i)
#pragma unroll
                for (int jj = 0; jj < 4; ++jj)
                    acc[i][jj] = fmaf(av[i], bv[jj], acc[i][jj]);
        }
        __syncthreads();
    }
    float bad[4];
#pragma unroll
    for (int jj = 0; jj < 4; ++jj)
        bad[jj] = b_ih[bn + tn + jj] + b_hh[bn + tn + jj];
#pragma unroll
    for (int i = 0; i < 4; ++i) {
        int m = bm + tm + i;
        if (m < 520)
            *(float4*)(xg0 + (size_t)m * 1024 + bn + tn) =
                make_float4(acc[i][0] + bad[0], acc[i][1] + bad[1],
                            acc[i][2] + bad[2], acc[i][3] + bad[3]);
    }
}

// ---------------------------------------------------------------------------
// cooperative mega-kernel: 160 blocks x 1024 threads.
//   blocks 0..31 : LSTM layer0 (8 j-rows each)     — dataflow-synced via S0
//   blocks 32..95: LSTM layer1 (4 j-rows each)     — S0/S1
//   blocks 96..159: dual-feat GEMM (attn_feat, hop_feat), 4x 64x64 tiles/block
// Weights pinned in VGPRs via asm (prevents compiler rematerialization).
// ---------------------------------------------------------------------------
__device__ __forceinline__ float dot16(const float4* w, const float* hp) {
    float4 s = make_float4(0.f, 0.f, 0.f, 0.f);
#pragma unroll
    for (int k = 0; k < 16; ++k) {
        float4 h4 = *(const float4*)(hp + 4 * k);
        s.x = fmaf(w[k].x, h4.x, s.x);
        s.y = fmaf(w[k].y, h4.y, s.y);
        s.z = fmaf(w[k].z, h4.z, s.z);
        s.w = fmaf(w[k].w, h4.w, s.w);
    }
    return (s.x + s.y) + (s.z + s.w);
}

// dual-issued poll of two adjacent (h,tag) u64 slots
__device__ __forceinline__ void poll2(const unsigned long long* p, unsigned want,
                                      float* d0, float* d1) {
    unsigned long long a = __hip_atomic_load(p,     __ATOMIC_RELAXED, __HIP_MEMORY_SCOPE_AGENT);
    unsigned long long b = __hip_atomic_load(p + 1, __ATOMIC_RELAXED, __HIP_MEMORY_SCOPE_AGENT);
    while ((unsigned)(a >> 32) != want)
        a = __hip_atomic_load(p, __ATOMIC_RELAXED, __HIP_MEMORY_SCOPE_AGENT);
    while ((unsigned)(b >> 32) != want)
        b = __hip_atomic_load(p + 1, __ATOMIC_RELAXED, __HIP_MEMORY_SCOPE_AGENT);
    *d0 = __uint_as_float((unsigned)a);
    *d1 = __uint_as_float((unsigned)b);
}

#define PIN16(w) do { _Pragma("unroll") \
    for (int _k = 0; _k < 16; ++_k) \
        asm volatile("" : "+v"(w[_k].x), "+v"(w[_k].y), "+v"(w[_k].z), "+v"(w[_k].w)); \
} while (0)

__global__ void __launch_bounds__(1024, 4) mega_kernel(
    const float* __restrict__ w_ih, const float* __restrict__ w_hh,
    const float* __restrict__ b_ih, const float* __restrict__ b_hh,
    const float* __restrict__ xg0, const float* __restrict__ init_c,
    unsigned long long* __restrict__ S0, unsigned long long* __restrict__ S1,
    float* __restrict__ query,
    const float* __restrict__ attn_mem, const float* __restrict__ attn_wm,
    const float* __restrict__ hop_wm,
    float* __restrict__ attn_feat, float* __restrict__ hop_feat)
{
    __shared__ float smem[13056];     // lstm: hls[4352]+part[1024]; feat: 4x3264
    const int tid = threadIdx.x;
    const int blk = blockIdx.x;

    if (blk >= 96) {
        // ---------------- dual-feat GEMM: 4 groups x 64x64 dual tile ----------
        const int grp = tid >> 8, tsub = tid & 255;
        const int tileid = (blk - 96) * 4 + grp;            // 0..255
        const int bm = (tileid & 63) * 64, bn = (tileid >> 6) * 64;
        float* As  = smem + grp * 3264;                     // [16][68]
        float* Bs  = As + 1088;
        float* Bs2 = As + 2176;
        const int tm = (tsub >> 4) * 4, tn = (tsub & 15) * 4;
        const int arow = tsub >> 2, akq = (tsub & 3) << 2;
        float acc1[4][4] = {}, acc2[4][4] = {};
        for (int k0 = 0; k0 < 256; k0 += 16) {
            float4 va = *(const float4*)(attn_mem + (size_t)(bm + arow) * 256 + k0 + akq);
            As[(akq + 0) * 68 + arow] = va.x; As[(akq + 1) * 68 + arow] = va.y;
            As[(akq + 2) * 68 + arow] = va.z; As[(akq + 3) * 68 + arow] = va.w;
            int kk = tsub >> 4, nq = (tsub & 15) << 2;
            *(float4*)&Bs[kk * 68 + nq]  = *(const float4*)(attn_wm + (size_t)(k0 + kk) * 256 + bn + nq);
            *(float4*)&Bs2[kk * 68 + nq] = *(const float4*)(hop_wm  + (size_t)(k0 + kk) * 256 + bn + nq);
            __syncthreads();
#pragma unroll
            for (int kk2 = 0; kk2 < 16; ++kk2) {
                float4 a  = *(const float4*)&As[kk2 * 68 + tm];
                float4 b1 = *(const float4*)&Bs[kk2 * 68 + tn];
                float4 b2 = *(const float4*)&Bs2[kk2 * 68 + tn];
                float av[4] = {a.x, a.y, a.z, a.w};
                float b1v[4] = {b1.x, b1.y, b1.z, b1.w};
                float b2v[4] = {b2.x, b2.y, b2.z, b2.w};
#pragma unroll
                for (int i = 0; i < 4; ++i)
#pragma unroll
                    for (int jj = 0; jj < 4; ++jj) {
                        acc1[i][jj] = fmaf(av[i], b1v[jj], acc1[i][jj]);
                        acc2[i][jj] = fmaf(av[i], b2v[jj], acc2[i][jj]);
                    }
            }
            __syncthreads();
        }
#pragma unroll
        for (int i = 0; i < 4; ++i) {
            int m = bm + tm + i;
            *(float4*)(attn_feat + (size_t)m * 256 + bn + tn) =
                make_float4(acc1[i][0], acc1[i][1], acc1[i][2], acc1[i][3]);
            *(float4*)(hop_feat + (size_t)m * 256 + bn + tn) =
                make_float4(acc2[i][0], acc2[i][1], acc2[i][2], acc2[i][3]);
        }
        return;
    }

    // -------------------------- LSTM ----------------------------------------
    float* hls  = smem;          // 64*68
    float* part = smem + 4352;   // 1024
    // staging map (thread stages payload pair 2tid, 2tid+1)
    const int g = tid * 2;
    const int sb = g >> 8, r0 = g & 255, sg0 = r0 >> 6, kq = r0 & 63;
    float* const dst = &hls[(sg0 * 8 + sb) * 68 + kq];

    if (blk < 32) {
        // ------------------------ layer 0 ------------------------
        const int jl = tid & 7, gate = (tid >> 3) & 3, b = (tid >> 5) & 7, seg = tid >> 8;
        const int j0 = blk * 8, j = j0 + jl;
        float4 w[16];
        {
            const float4* wr = (const float4*)(w_hh + (size_t)(gate * HH + j) * HH + seg * 64);
#pragma unroll
            for (int k = 0; k < 16; ++k) w[k] = wr[k];
        }
        PIN16(w);   // force register residency across the t loop
        const int fj = tid >> 3, fb = tid & 7;   // finisher mapping (tid<64)
        float creg = (tid < 64) ? init_c[j0 + fj] : 0.f;
        const int chunk = seg * 8 + b;
        const int pidx = (chunk * 8 + jl) * 4 + gate;

        for (int t = 0; t < SS; ++t) {
            float xg[4];
            if (tid < 64) {
                const float* xp = xg0 + ((size_t)fb * SS + t) * G4 + (j0 + fj);
#pragma unroll
                for (int gg = 0; gg < 4; ++gg) xg[gg] = xp[gg * 256];
            }
            poll2(S0 + (size_t)t * 2048 + g, (unsigned)(t + 1), &dst[0], &dst[1]);
            __syncthreads();
            part[pidx] = dot16(w, &hls[chunk * 68]);
            __syncthreads();
            if (tid < 64) {
                float g0 = xg[0], g1 = xg[1], g2 = xg[2], g3 = xg[3];
#pragma unroll
                for (int s2 = 0; s2 < 4; ++s2) {
                    const float* pp = &part[((s2 * 8 + fb) * 8 + fj) * 4];
                    g0 += pp[0]; g1 += pp[1]; g2 += pp[2]; g3 += pp[3];
                }
                float c = fsigmoid(g1) * creg + fsigmoid(g0) * ftanh(g2);
                float h = fsigmoid(g3) * ftanh(c);
                creg = c;
                unsigned long long u = ((unsigned long long)(unsigned)(t + 2) << 32)
                                     | (unsigned long long)(unsigned)__float_as_uint(h);
                __hip_atomic_store(S0 + (size_t)(t + 1) * 2048 + fb * 256 + (j0 + fj), u,
                                   __ATOMIC_RELAXED, __HIP_MEMORY_SCOPE_AGENT);
            }
        }
    } else {
        // ------------------------ layer 1 ------------------------
        const int jl = tid & 3, gate = (tid >> 2) & 3, b = (tid >> 4) & 7, seg = tid >> 7;
        const int j0 = (blk - 32) * 4, j = j0 + jl;
        float4 w[16];
        {
            const float* base = (seg < 4)
                ? (w_ih + (size_t)(G4 + gate * HH + j) * HH + seg * 64)
                : (w_hh + (size_t)(G4 + gate * HH + j) * HH + (seg - 4) * 64);
            const float4* wr = (const float4*)base;
#pragma unroll
            for (int k = 0; k < 16; ++k) w[k] = wr[k];
        }
        PIN16(w);
        const int fj = tid >> 3, fb = tid & 7;   // finisher mapping (tid<32)
        float creg = 0.f, bias[4] = {0.f, 0.f, 0.f, 0.f};
        if (tid < 32) {
            creg = init_c[HH + j0 + fj];
#pragma unroll
            for (int gg = 0; gg < 4; ++gg)
                bias[gg] = b_ih[G4 + gg * HH + j0 + fj] + b_hh[G4 + gg * HH + j0 + fj];
        }
        const int chunk = seg * 8 + b;
        const int pidx = chunk * 16 + jl * 4 + gate;

        for (int t = 0; t < SS; ++t) {
            poll2(S0 + (size_t)(t + 1) * 2048 + g, (unsigned)(t + 2), &dst[0], &dst[1]);
            __syncthreads();
            if (seg < 4) part[pidx] = dot16(w, &hls[chunk * 68]);
            poll2(S1 + (size_t)t * 2048 + g, (unsigned)(t + 1),
                  &dst[32 * 68], &dst[32 * 68 + 1]);
            __syncthreads();
            if (seg >= 4) part[pidx] = dot16(w, &hls[chunk * 68]);  // chunk in 32..63
            __syncthreads();
            if (tid < 32) {
                float g0 = bias[0], g1 = bias[1], g2 = bias[2], g3 = bias[3];
#pragma unroll
                for (int s2 = 0; s2 < 8; ++s2) {
                    const float* pp = &part[(s2 * 8 + fb) * 16 + fj * 4];
                    g0 += pp[0]; g1 += pp[1]; g2 += pp[2]; g3 += pp[3];
                }
                float c = fsigmoid(g1) * creg + fsigmoid(g0) * ftanh(g2);
                float h = fsigmoid(g3) * ftanh(c);
                creg = c;
                int jj = j0 + fj;
                unsigned long long u = ((unsigned long long)(unsigned)(t + 2) << 32)
                                     | (unsigned long long)(unsigned)__float_as_uint(h);
                __hip_atomic_store(S1 + (size_t)(t + 1) * 2048 + fb * 256 + jj, u,
                                   __ATOMIC_RELAXED, __HIP_MEMORY_SCOPE_AGENT);
                query[((size_t)fb * SS + t) * HH + jj] = h;
            }
        }
    }
}

// ---------------------------------------------------------------------------
// fused post-LSTM chain, one block per (s,b):
//   q1 = query_row @ hop_wq
//   sc[n] = sum_h tanh(hop_feat+q1)*hop_v   (n < msize)
//   p = softmax(sc)  ;  q2raw[h] = sum_n p[n]*hop_feat[n][h]
//   q2 = q2raw @ attn_wq
//   out[n] = sum_h tanh(attn_feat+q2)*attn_v   (all 512 n, unmasked per ref)
// ---------------------------------------------------------------------------
__global__ void __launch_bounds__(256) post_kernel(
    const float* __restrict__ query, const float* __restrict__ hop_wq,
    const float* __restrict__ hop_feat, const float* __restrict__ hop_v,
    const float* __restrict__ attn_wq, const float* __restrict__ attn_feat,
    const float* __restrict__ attn_v, const int* __restrict__ mem_sizes,
    float* __restrict__ out)
{
    const int s = blockIdx.x, b = blockIdx.y, tid = threadIdx.x;
    __shared__ float qa[256];    // query row -> later q2raw
    __shared__ float qb[256];    // q1 -> later q2
    __shared__ float vv[256];    // hop_v -> later attn_v
    __shared__ float sc[512];
    __shared__ float red[8];
    const int msize = mem_sizes[b];
    const int lane = tid & 63, wv = tid >> 6;

    qa[tid] = query[((size_t)b * SS + s) * HH + tid];
    vv[tid] = hop_v[tid];
    __syncthreads();
    {   // q1 = qa @ hop_wq
        float a = 0.f;
        const float* wp = hop_wq + tid;
#pragma unroll 4
        for (int h = 0; h < 256; ++h) a = fmaf(qa[h], wp[(size_t)h * 256], a);
        qb[tid] = a;
    }
    __syncthreads();
    {   // hop scores, wave per n
        float4 q4 = *(const float4*)&qb[lane << 2];
        float4 v4 = *(const float4*)&vv[lane << 2];
        const float* fb = hop_feat + (size_t)b * NN * HH + (lane << 2);
        for (int n = wv; n < msize; n += 4) {
            float4 f4 = *(const float4*)(fb + (size_t)n * HH);
            float a = ftanh(f4.x + q4.x) * v4.x + ftanh(f4.y + q4.y) * v4.y
                    + ftanh(f4.z + q4.z) * v4.z + ftanh(f4.w + q4.w) * v4.w;
#pragma unroll
            for (int off = 32; off; off >>= 1) a += __shfl_xor(a, off, 64);
            if (lane == 0) sc[n] = a;
        }
    }
    __syncthreads();
    {   // softmax over sc[0..msize)
        float x0 = (tid < msize) ? sc[tid] : -3e38f;
        float x1 = (tid + 256 < msize) ? sc[tid + 256] : -3e38f;
        float m = fmaxf(x0, x1);
#pragma unroll
        for (int off = 32; off; off >>= 1) m = fmaxf(m, __shfl_xor(m, off, 64));
        if (lane == 0) red[wv] = m;
        __syncthreads();
        m = fmaxf(fmaxf(red[0], red[1]), fmaxf(red[2], red[3]));
        float e0 = __expf(x0 - m), e1 = __expf(x1 - m);
        float l = e0 + e1;
#pragma unroll
        for (int off = 32; off; off >>= 1) l += __shfl_xor(l, off, 64);
        if (lane == 0) red[4 + wv] = l;
        __syncthreads();
        float inv = __builtin_amdgcn_rcpf(red[4] + red[5] + red[6] + red[7]);
        sc[tid] = e0 * inv;
        sc[tid + 256] = e1 * inv;
    }
    __syncthreads();
    {   // q2raw[tid] = sum_n p[n] * hop_feat[b][n][tid]
        float a = 0.f;
        const float* fb = hop_feat + (size_t)b * NN * HH + tid;
        int n = 0;
        for (; n + 4 <= msize; n += 4) {
            a = fmaf(sc[n + 0], fb[(size_t)(n + 0) * HH], a);
            a = fmaf(sc[n + 1], fb[(size_t)(n + 1) * HH], a);
            a = fmaf(sc[n + 2], fb[(size_t)(n + 2) * HH], a);
            a = fmaf(sc[n + 3], fb[(size_t)(n + 3) * HH], a);
        }
        for (; n < msize; ++n) a = fmaf(sc[n], fb[(size_t)n * HH], a);
        __syncthreads();
        qa[tid] = a;
    }
    __syncthreads();
    {   // q2 = qa @ attn_wq ; also swap v to attn_v
        float a = 0.f;
        const float* wp = attn_wq + tid;
#pragma unroll 4
        for (int h = 0; h < 256; ++h) a = fmaf(qa[h], wp[(size_t)h * 256], a);
        qb[tid] = a;
        vv[tid] = attn_v[tid];
    }
    __syncthreads();
    {   // final scores (unmasked, all n per reference)
        float4 q4 = *(const float4*)&qb[lane << 2];
        float4 v4 = *(const float4*)&vv[lane << 2];
        const float* fb = attn_feat + (size_t)b * NN * HH + (lane << 2);
        float* ob = out + ((size_t)b * SS + s) * NN;
        for (int n = wv; n < NN; n += 4) {
            float4 f4 = *(const float4*)(fb + (size_t)n * HH);
            float a = ftanh(f4.x + q4.x) * v4.x + ftanh(f4.y + q4.y) * v4.y
                    + ftanh(f4.z + q4.z) * v4.z + ftanh(f4.w + q4.w) * v4.w;
#pragma unroll
            for (int off = 32; off; off >>= 1) a += __shfl_xor(a, off, 64);
            if (lane == 0) ob[n] = a;
        }
    }
}

// ---------------------------------------------------------------------------
extern "C" void kernel_launch(void* const* d_in, const int* in_sizes, int n_in,
                              void* d_out, int out_size, void* d_ws, size_t ws_size,
                              hipStream_t stream) {
    const float* attn_mem  = (const float*)d_in[0];
    const int*   mem_sizes = (const int*)d_in[1];
    const float* lstm_in   = (const float*)d_in[2];
    const float* init_h    = (const float*)d_in[3];
    const float* init_c    = (const float*)d_in[4];
    const float* init_i    = (const float*)d_in[5];
    const float* w_ih      = (const float*)d_in[6];
    const float* w_hh      = (const float*)d_in[7];
    const float* b_ih      = (const float*)d_in[8];
    const float* b_hh      = (const float*)d_in[9];
    const float* attn_wm   = (const float*)d_in[10];
    const float* attn_wq   = (const float*)d_in[11];
    const float* attn_v    = (const float*)d_in[12];
    const float* hop_wm    = (const float*)d_in[13];
    const float* hop_wq    = (const float*)d_in[14];
    const float* hop_v     = (const float*)d_in[15];
    float* out = (float*)d_out;

    float* ws        = (float*)d_ws;
    float* attn_feat = ws;                 // 1,048,576 floats
    float* hop_feat  = ws + 1048576;       // 1,048,576
    float* xg0       = ws + 2097152;       //   532,480
    float* query     = ws + 2629632;       //   133,120
    unsigned long long* S0 = (unsigned long long*)(ws + 2762752); // 135,168 u64
    unsigned long long* S1 = (unsigned long long*)(ws + 3033088); // 135,168 u64

    xgprep_kernel<<<1200, 256, 0, stream>>>(lstm_in, init_i, init_h, w_ih,
                                            b_ih, b_hh, xg0, S0, S1);
    {
        void* args[] = { (void*)&w_ih, (void*)&w_hh, (void*)&b_ih, (void*)&b_hh,
                         (void*)&xg0, (void*)&init_c, (void*)&S0, (void*)&S1,
                         (void*)&query, (void*)&attn_mem, (void*)&attn_wm,
                         (void*)&hop_wm, (void*)&attn_feat, (void*)&hop_feat };
        hipLaunchCooperativeKernel(mega_kernel, dim3(160), dim3(1024), args, 0u, stream);
    }
    post_kernel<<<dim3(65, 8), 256, 0, stream>>>(query, hop_wq, hop_feat, hop_v,
                                                 attn_wq, attn_feat, attn_v,
                                                 mem_sizes, out);
}